// Round 8
// baseline (66.939 us; speedup 1.0000x reference)
//
#include <hip/hip_runtime.h>

typedef __attribute__((ext_vector_type(4))) float f32x4;
typedef __attribute__((ext_vector_type(4))) unsigned int u32x4;
typedef __attribute__((ext_vector_type(8))) short short8;
typedef __attribute__((ext_vector_type(8))) __bf16 bf16x8;

constexpr int kN = 4096;
constexpr int kF = 256;
constexpr int kH = 4;
constexpr int kD = 64;
constexpr float kLog2e = 1.4426950408889634f;

__device__ __forceinline__ unsigned short f2us(float x) {
  __bf16 b = (__bf16)x;
  return __builtin_bit_cast(unsigned short, b);
}

// ---------------------------------------------------------------------------
// k_wswz: W (fp32, HxFxD) -> bf16 MFMA B-fragments for k_wh. Zeroes MhKey.
// ---------------------------------------------------------------------------
__global__ __launch_bounds__(256) void k_wswz(const float* __restrict__ W,
                                              unsigned short* __restrict__ wfrag,
                                              unsigned int* __restrict__ MhKey) {
  const int h = blockIdx.x;
  const int t = threadIdx.x;
  if (t == 0) MhKey[h] = 0u;
#pragma unroll
  for (int j = 0; j < 8; j++) {
    const int lf = t + j * 256;  // 0..2047
    const int lane = lf & 63;
    const int dt = (lf >> 6) & 3;
    const int ks = lf >> 8;
    const int d = dt * 16 + (lane & 15);
    const int i0 = ks * 32 + 8 * (lane >> 4);
    unsigned short v[8];
#pragma unroll
    for (int e = 0; e < 8; e++)
      v[e] = f2us(W[((size_t)h * kF + i0 + e) * kD + d]);
    *reinterpret_cast<short8*>(wfrag + ((size_t)(h * 2048 + lf) << 3)) =
        *reinterpret_cast<const short8*>(v);
  }
}

// ---------------------------------------------------------------------------
// k_wh: Wh = h @ W[h] via MFMA; writes whb (bf16, pre-swizzled B-frag order)
// + s_src/s_dst + atomicMax'ed max-key.
// ---------------------------------------------------------------------------
__global__ __launch_bounds__(256) void k_wh(const float* __restrict__ hmat,
                                            const unsigned short* __restrict__ wfrag,
                                            const float* __restrict__ a_src,
                                            const float* __restrict__ a_dst,
                                            unsigned short* __restrict__ whb,
                                            float* __restrict__ s_src,
                                            float* __restrict__ s_dst,
                                            unsigned int* __restrict__ MhKey) {
  const int h = blockIdx.x & 3, rb = blockIdx.x >> 2;
  const int row0 = rb * 64;
  const int t = threadIdx.x;
  const int wave = t >> 6, lane = t & 63;
  const int lr = lane & 15, lg = lane >> 4;
  const int nrow = row0 + wave * 16 + lr;
  f32x4 acc[4] = {};
  const float* hrow = hmat + (size_t)nrow * kF + 8 * lg;
  const short8* wf = reinterpret_cast<const short8*>(wfrag) + h * 2048 + lane;
#pragma unroll
  for (int ks = 0; ks < 8; ks++) {
    const f32x4 h0 = *reinterpret_cast<const f32x4*>(hrow + ks * 32);
    const f32x4 h1 = *reinterpret_cast<const f32x4*>(hrow + ks * 32 + 4);
    bf16x8 af;
#pragma unroll
    for (int j = 0; j < 4; j++) { af[j] = (__bf16)h0[j]; af[4 + j] = (__bf16)h1[j]; }
#pragma unroll
    for (int dt = 0; dt < 4; dt++) {
      const short8 bs = wf[(ks * 4 + dt) * 64];
      acc[dt] = __builtin_amdgcn_mfma_f32_16x16x32_bf16(af, __builtin_bit_cast(bf16x8, bs), acc[dt], 0, 0, 0);
    }
  }
#pragma unroll
  for (int dt = 0; dt < 4; dt++) {
#pragma unroll
    for (int r = 0; r < 4; r++) {
      const int n = row0 + wave * 16 + lg * 4 + r;
      const int mstep = n >> 5, kl = n & 31;
      const int lane2 = ((kl >> 3) << 4) | lr;
      const int e = kl & 7;
      whb[((((size_t)(h * 128 + mstep) * 4 + dt) * 64 + lane2) << 3) + e] = f2us(acc[dt][r]);
    }
  }
  float as4[4], ad4[4];
#pragma unroll
  for (int dt = 0; dt < 4; dt++) {
    as4[dt] = a_src[h * kD + dt * 16 + lr];
    ad4[dt] = a_dst[h * kD + dt * 16 + lr];
  }
  float wmax = -1e30f;
#pragma unroll
  for (int r = 0; r < 4; r++) {
    float ps = acc[0][r] * as4[0] + acc[1][r] * as4[1] + acc[2][r] * as4[2] + acc[3][r] * as4[3];
    float pd = acc[0][r] * ad4[0] + acc[1][r] * ad4[1] + acc[2][r] * ad4[2] + acc[3][r] * ad4[3];
#pragma unroll
    for (int off = 1; off < 16; off <<= 1) {
      ps += __shfl_xor(ps, off);
      pd += __shfl_xor(pd, off);
    }
    const int n = row0 + wave * 16 + lg * 4 + r;
    if (lr == 0) { s_src[h * kN + n] = ps; s_dst[h * kN + n] = pd; }
    wmax = fmaxf(wmax, pd);
  }
  wmax = fmaxf(wmax, __shfl_xor(wmax, 16));
  wmax = fmaxf(wmax, __shfl_xor(wmax, 32));
  if (lane == 0) {
    const unsigned int key = (unsigned int)fmaxf(0.0f, (wmax + 512.0f) * 4096.0f) + 1u;
    atomicMax(&MhKey[h], key);
  }
}

// ---------------------------------------------------------------------------
// k_abits: adj (fp32 0/1) -> TRANSPOSED bitmask bitsT (unchanged layout:
// each k_attn lane's 32 iteration-bytes contiguous per row).
// ---------------------------------------------------------------------------
__global__ __launch_bounds__(256) void k_abits(const float* __restrict__ adj,
                                               unsigned char* __restrict__ bitsT) {
  const int gw = (blockIdx.x * 256 + threadIdx.x) >> 6;  // wave id, 16384 total
  const int lane = threadIdx.x & 63;
  const int r = gw >> 2, cb = gw & 3;
  const size_t ebase = (size_t)gw * 1024;
  const float* p = adj + ebase + lane;
  unsigned int myword = 0;
#pragma unroll
  for (int c = 0; c < 16; c++) {
    const unsigned long long b = __ballot(p[c * 64] != 0.0f);
    const unsigned int sel = (lane & 1) ? (unsigned int)(b >> 32) : (unsigned int)b;
    if ((lane >> 1) == c) myword = sel;
  }
  if (lane < 32) {
    const int w = cb * 32 + lane;  // word index within row, covers cols [w*32, +32)
    const int cs = w >> 6, rem = w & 63;
    const int q = rem & 1, it = rem >> 1;
    const size_t base = (size_t)r * 512 + (size_t)it;
#pragma unroll
    for (int k = 0; k < 4; k++)
      bitsT[base + (size_t)((cs << 3) + (q << 2) + k) * 32] =
          (unsigned char)((myword >> (8 * k)) & 0xFFu);
  }
}

// p = mask * max(E1*K1, E2*K2)
__device__ __forceinline__ bf16x8 make_p2(const f32x4 E1a, const f32x4 E1b,
                                          const f32x4 E2a, const f32x4 E2b,
                                          const float K1, const float K2,
                                          const unsigned int m) {
  bf16x8 r;
#pragma unroll
  for (int j = 0; j < 4; j++) {
    const float pv = fmaxf(E1a[j] * K1, E2a[j] * K2);
    r[j] = (__bf16)((m & (1u << j)) ? pv : 0.0f);
  }
#pragma unroll
  for (int j = 0; j < 4; j++) {
    const float pv = fmaxf(E1b[j] * K1, E2b[j] * K2);
    r[4 + j] = (__bf16)((m & (16u << j)) ? pv : 0.0f);
  }
  return r;
}

// ---------------------------------------------------------------------------
// k_attn: 256 blocks = 128 rowgroups(32 rows) x 2 col-halves(2048).
// 8 waves = 4 heads x 2 col-interleaves (q). Each wave processes TWO 16-row
// tiles against the SAME B-fragments (halves L2 Wh traffic, the round-7
// bottleneck). Masks in registers (4 dwordx4). q partials combined via LDS.
// ---------------------------------------------------------------------------
__global__ __launch_bounds__(512, 2) void k_attn(const unsigned char* __restrict__ bitsT,
                                                 const unsigned short* __restrict__ whb,
                                                 const float* __restrict__ s_src,
                                                 const float* __restrict__ s_dst,
                                                 const unsigned int* __restrict__ MhKey,
                                                 float* __restrict__ accP,
                                                 float* __restrict__ zP) {
  const int bid = blockIdx.x;
  const int rb = bid >> 1, cs = bid & 1;
  const int row0 = rb * 32;
  const int colbase = cs * 2048;
  const int t = threadIdx.x;
  const int wave = t >> 6, lane = t & 63;
  const int h = wave & 3, q = wave >> 2;
  const int lr = lane & 15, lg = lane >> 4;

  __shared__ float el1[4][2048];
  __shared__ float el2[4][2048];
  __shared__ float zx[4][32];

#pragma unroll
  for (int j = 0; j < 4; j++) {
    const int idx = t + j * 512;  // 0..2047 f32x4 slots
    const int hh = idx >> 9, c4 = (idx & 511) * 4;
    const f32x4 sd = *reinterpret_cast<const f32x4*>(s_dst + hh * kN + colbase + c4);
    f32x4 e1, e2;
#pragma unroll
    for (int i = 0; i < 4; i++) {
      const float u = sd[i] * kLog2e;
      e1[i] = __builtin_amdgcn_exp2f(u);
      e2[i] = __builtin_amdgcn_exp2f(0.2f * u);
    }
    *reinterpret_cast<f32x4*>(&el1[hh][c4]) = e1;
    *reinterpret_cast<f32x4*>(&el2[hh][c4]) = e2;
  }
  __syncthreads();

  const float M = (float)MhKey[h] * (1.0f / 4096.0f) - 512.0f;
  float K1[2], K2[2];
#pragma unroll
  for (int rt = 0; rt < 2; rt++) {
    const float A = s_src[h * kN + row0 + rt * 16 + lr];
    const float xb = A + M;
    const float B = fmaxf(xb, 0.2f * xb);
    K1[rt] = __builtin_amdgcn_exp2f((A - B) * kLog2e);
    K2[rt] = __builtin_amdgcn_exp2f((0.2f * A - B) * kLog2e);
  }

  f32x4 acc0[4] = {}, acc1[4] = {};
  f32x4 accz0 = {}, accz1 = {};
  bf16x8 ones;
#pragma unroll
  for (int e = 0; e < 8; e++) ones[e] = (__bf16)1.0f;

  // masks: 32 contiguous iteration-bytes per lane per row-tile
  const size_t mBase0 = (size_t)(row0 + lr) * 512 + (size_t)((cs << 3) + (q << 2) + lg) * 32;
  const size_t mBase1 = mBase0 + (size_t)16 * 512;
  const u32x4 ma0 = *reinterpret_cast<const u32x4*>(bitsT + mBase0);       // rt0 it 0..15
  const u32x4 ma1 = *reinterpret_cast<const u32x4*>(bitsT + mBase0 + 16);  // rt0 it 16..31
  const u32x4 mb0 = *reinterpret_cast<const u32x4*>(bitsT + mBase1);       // rt1 it 0..15
  const u32x4 mb1 = *reinterpret_cast<const u32x4*>(bitsT + mBase1 + 16);  // rt1 it 16..31

  const float* e1p = &el1[h][q * 32 + 8 * lg];
  const float* e2p = &el2[h][q * 32 + 8 * lg];
  const short8* wb = reinterpret_cast<const short8*>(whb) + (size_t)h * 32768 + lane;
  const int mstep0 = cs * 64 + q;

  // 2-deep B-frag prefetch (unguarded overflow prefetches land in-ws, unused)
  short8 bw[2][4];
#pragma unroll
  for (int s = 0; s < 2; s++) {
    const short8* p = wb + (size_t)(mstep0 + s * 2) * 256;
    bw[s][0] = p[0]; bw[s][1] = p[64]; bw[s][2] = p[128]; bw[s][3] = p[192];
  }

#define UNIT(ITC, CM0, CM1)                                                    \
  {                                                                            \
    const short8 cb0 = bw[(ITC) & 1][0], cb1 = bw[(ITC) & 1][1],               \
                 cb2 = bw[(ITC) & 1][2], cb3 = bw[(ITC) & 1][3];               \
    const short8* pp = wb + (size_t)(mstep0 + ((ITC) + 2) * 2) * 256;          \
    bw[(ITC) & 1][0] = pp[0];                                                  \
    bw[(ITC) & 1][1] = pp[64];                                                 \
    bw[(ITC) & 1][2] = pp[128];                                                \
    bw[(ITC) & 1][3] = pp[192];                                                \
    const f32x4 E1a = *reinterpret_cast<const f32x4*>(e1p + (ITC) * 64);       \
    const f32x4 E1b = *reinterpret_cast<const f32x4*>(e1p + (ITC) * 64 + 4);   \
    const f32x4 E2a = *reinterpret_cast<const f32x4*>(e2p + (ITC) * 64);       \
    const f32x4 E2b = *reinterpret_cast<const f32x4*>(e2p + (ITC) * 64 + 4);   \
    const bf16x8 P0 = make_p2(E1a, E1b, E2a, E2b, K1[0], K2[0], (CM0));        \
    const bf16x8 P1 = make_p2(E1a, E1b, E2a, E2b, K1[1], K2[1], (CM1));        \
    const bf16x8 B0 = __builtin_bit_cast(bf16x8, cb0);                         \
    const bf16x8 B1 = __builtin_bit_cast(bf16x8, cb1);                         \
    const bf16x8 B2 = __builtin_bit_cast(bf16x8, cb2);                         \
    const bf16x8 B3 = __builtin_bit_cast(bf16x8, cb3);                         \
    acc0[0] = __builtin_amdgcn_mfma_f32_16x16x32_bf16(P0, B0, acc0[0], 0, 0, 0); \
    acc1[0] = __builtin_amdgcn_mfma_f32_16x16x32_bf16(P1, B0, acc1[0], 0, 0, 0); \
    acc0[1] = __builtin_amdgcn_mfma_f32_16x16x32_bf16(P0, B1, acc0[1], 0, 0, 0); \
    acc1[1] = __builtin_amdgcn_mfma_f32_16x16x32_bf16(P1, B1, acc1[1], 0, 0, 0); \
    acc0[2] = __builtin_amdgcn_mfma_f32_16x16x32_bf16(P0, B2, acc0[2], 0, 0, 0); \
    acc1[2] = __builtin_amdgcn_mfma_f32_16x16x32_bf16(P1, B2, acc1[2], 0, 0, 0); \
    acc0[3] = __builtin_amdgcn_mfma_f32_16x16x32_bf16(P0, B3, acc0[3], 0, 0, 0); \
    acc1[3] = __builtin_amdgcn_mfma_f32_16x16x32_bf16(P1, B3, acc1[3], 0, 0, 0); \
    accz0 = __builtin_amdgcn_mfma_f32_16x16x32_bf16(P0, ones, accz0, 0, 0, 0); \
    accz1 = __builtin_amdgcn_mfma_f32_16x16x32_bf16(P1, ones, accz1, 0, 0, 0); \
  }

#pragma unroll
  for (int it = 0; it < 16; ++it) {
    const unsigned cm0 = (ma0[it >> 2] >> ((it & 3) * 8)) & 0xFFu;
    const unsigned cm1 = (mb0[it >> 2] >> ((it & 3) * 8)) & 0xFFu;
    UNIT(it, cm0, cm1);
  }
#pragma unroll
  for (int it2 = 0; it2 < 16; ++it2) {
    const int it = it2 + 16;
    const unsigned cm0 = (ma1[it2 >> 2] >> ((it2 & 3) * 8)) & 0xFFu;
    const unsigned cm1 = (mb1[it2 >> 2] >> ((it2 & 3) * 8)) & 0xFFu;
    UNIT(it, cm0, cm1);
  }
#undef UNIT

  // ---- q-combine via LDS (el1/el2 dead now), then single plain store ----
  __syncthreads();
  if (q == 1) {
#pragma unroll
    for (int dt = 0; dt < 4; dt++) {
      *reinterpret_cast<f32x4*>(&el1[h][(dt * 64 + lane) * 4]) = acc0[dt];
      *reinterpret_cast<f32x4*>(&el2[h][(dt * 64 + lane) * 4]) = acc1[dt];
    }
    if (lr == 0) {
#pragma unroll
      for (int r = 0; r < 4; r++) {
        zx[h][lg * 4 + r] = accz0[r];
        zx[h][16 + lg * 4 + r] = accz1[r];
      }
    }
  }
  __syncthreads();
  if (q == 0) {
#pragma unroll
    for (int dt = 0; dt < 4; dt++) {
      acc0[dt] += *reinterpret_cast<const f32x4*>(&el1[h][(dt * 64 + lane) * 4]);
      acc1[dt] += *reinterpret_cast<const f32x4*>(&el2[h][(dt * 64 + lane) * 4]);
    }
    const size_t ob = ((size_t)(cs * 4 + h) * kN + row0) * kD;
#pragma unroll
    for (int dt = 0; dt < 4; dt++)
#pragma unroll
      for (int r = 0; r < 4; r++) {
        accP[ob + (size_t)(lg * 4 + r) * kD + dt * 16 + lr] = acc0[dt][r];
        accP[ob + (size_t)(16 + lg * 4 + r) * kD + dt * 16 + lr] = acc1[dt][r];
      }
    if (lr == 0) {
      const size_t zb = (size_t)(cs * 4 + h) * kN + row0;
#pragma unroll
      for (int r = 0; r < 4; r++) {
        zP[zb + lg * 4 + r] = accz0[r] + zx[h][lg * 4 + r];
        zP[zb + 16 + lg * 4 + r] = accz1[r] + zx[h][16 + lg * 4 + r];
      }
    }
  }
}

// ---------------------------------------------------------------------------
// k_fin: out[n][h*64+d] = elu( (acc0+acc1) / (z0+z1) )
// ---------------------------------------------------------------------------
__global__ __launch_bounds__(256) void k_fin(const float* __restrict__ accP,
                                             const float* __restrict__ zP,
                                             float* __restrict__ out) {
  const int idx = blockIdx.x * 256 + threadIdx.x;  // 262144 float4s
  const int d4 = idx & 15;
  const int hh = (idx >> 4) & 3;
  const int n = idx >> 6;
  const f32x4 v0 = reinterpret_cast<const f32x4*>(accP)[((size_t)hh * kN + n) * 16 + d4];
  const f32x4 v1 = reinterpret_cast<const f32x4*>(accP)[((size_t)(4 + hh) * kN + n) * 16 + d4];
  const f32x4 v = v0 + v1;
  const float z = zP[(size_t)hh * kN + n] + zP[(size_t)(4 + hh) * kN + n];
  const float rz = 1.0f / z;
  f32x4 o;
#pragma unroll
  for (int j = 0; j < 4; j++) {
    const float x = v[j] * rz;
    o[j] = x > 0.0f ? x : (__builtin_amdgcn_exp2f(x * kLog2e) - 1.0f);
  }
  reinterpret_cast<f32x4*>(out)[(size_t)n * 64 + hh * 16 + d4] = o;
}

extern "C" void kernel_launch(void* const* d_in, const int* in_sizes, int n_in,
                              void* d_out, int out_size, void* d_ws, size_t ws_size,
                              hipStream_t stream) {
  const float* hmat  = (const float*)d_in[0];
  const float* adj   = (const float*)d_in[1];
  const float* W     = (const float*)d_in[2];
  const float* a_src = (const float*)d_in[3];
  const float* a_dst = (const float*)d_in[4];
  float* out = (float*)d_out;

  char* ws = (char*)d_ws;
  unsigned short* whb   = (unsigned short*)(ws);             // 2 MB    @0
  unsigned short* wfrag = (unsigned short*)(ws + 0x200000);  // 128 KB (dead after k_wh)
  float* zP     = (float*)(ws + 0x200000);                   // 128 KB (reuses wfrag)
  float* s_src  = (float*)(ws + 0x220000);                   // 64 KB
  float* s_dst  = (float*)(ws + 0x230000);                   // 64 KB
  unsigned int* MhKey = (unsigned int*)(ws + 0x240000);      // 64 B
  unsigned char* bitsT = (unsigned char*)(ws + 0x241000);    // 2 MB (transposed)
  float* accP   = (float*)(ws + 0x441000);                   // 8 MB (2 col-splits)

  hipLaunchKernelGGL(k_wswz, dim3(4), dim3(256), 0, stream, W, wfrag, MhKey);
  hipLaunchKernelGGL(k_wh, dim3(256), dim3(256), 0, stream,
                     hmat, wfrag, a_src, a_dst, whb, s_src, s_dst, MhKey);
  hipLaunchKernelGGL(k_abits, dim3(4096), dim3(256), 0, stream, adj, bitsT);
  hipLaunchKernelGGL(k_attn, dim3(256), dim3(512), 0, stream,
                     bitsT, whb, s_src, s_dst, MhKey, accP, zP);
  hipLaunchKernelGGL(k_fin, dim3(1024), dim3(256), 0, stream, accP, zP, out);
}

// Round 9
// 65.256 us; speedup vs baseline: 1.0258x; 1.0258x over previous
//
#include <hip/hip_runtime.h>

typedef __attribute__((ext_vector_type(4))) float f32x4;
typedef __attribute__((ext_vector_type(4))) unsigned int u32x4;
typedef __attribute__((ext_vector_type(8))) short short8;
typedef __attribute__((ext_vector_type(8))) __bf16 bf16x8;

constexpr int kN = 4096;
constexpr int kF = 256;
constexpr int kH = 4;
constexpr int kD = 64;
constexpr float kLog2e = 1.4426950408889634f;

__device__ __forceinline__ unsigned short f2us(float x) {
  __bf16 b = (__bf16)x;
  return __builtin_bit_cast(unsigned short, b);
}

// ---------------------------------------------------------------------------
// k_wswz: W (fp32, HxFxD) -> bf16 MFMA B-fragments for k_wh. Zeroes MhKey.
// ---------------------------------------------------------------------------
__global__ __launch_bounds__(256) void k_wswz(const float* __restrict__ W,
                                              unsigned short* __restrict__ wfrag,
                                              unsigned int* __restrict__ MhKey) {
  const int h = blockIdx.x;
  const int t = threadIdx.x;
  if (t == 0) MhKey[h] = 0u;
#pragma unroll
  for (int j = 0; j < 8; j++) {
    const int lf = t + j * 256;  // 0..2047
    const int lane = lf & 63;
    const int dt = (lf >> 6) & 3;
    const int ks = lf >> 8;
    const int d = dt * 16 + (lane & 15);
    const int i0 = ks * 32 + 8 * (lane >> 4);
    unsigned short v[8];
#pragma unroll
    for (int e = 0; e < 8; e++)
      v[e] = f2us(W[((size_t)h * kF + i0 + e) * kD + d]);
    *reinterpret_cast<short8*>(wfrag + ((size_t)(h * 2048 + lf) << 3)) =
        *reinterpret_cast<const short8*>(v);
  }
}

// ---------------------------------------------------------------------------
// k_wh: Wh = h @ W[h] via MFMA; writes whb (bf16, pre-swizzled B-frag order)
// + s_src/s_dst + atomicMax'ed max-key.
// ---------------------------------------------------------------------------
__global__ __launch_bounds__(256) void k_wh(const float* __restrict__ hmat,
                                            const unsigned short* __restrict__ wfrag,
                                            const float* __restrict__ a_src,
                                            const float* __restrict__ a_dst,
                                            unsigned short* __restrict__ whb,
                                            float* __restrict__ s_src,
                                            float* __restrict__ s_dst,
                                            unsigned int* __restrict__ MhKey) {
  const int h = blockIdx.x & 3, rb = blockIdx.x >> 2;
  const int row0 = rb * 64;
  const int t = threadIdx.x;
  const int wave = t >> 6, lane = t & 63;
  const int lr = lane & 15, lg = lane >> 4;
  const int nrow = row0 + wave * 16 + lr;
  f32x4 acc[4] = {};
  const float* hrow = hmat + (size_t)nrow * kF + 8 * lg;
  const short8* wf = reinterpret_cast<const short8*>(wfrag) + h * 2048 + lane;
#pragma unroll
  for (int ks = 0; ks < 8; ks++) {
    const f32x4 h0 = *reinterpret_cast<const f32x4*>(hrow + ks * 32);
    const f32x4 h1 = *reinterpret_cast<const f32x4*>(hrow + ks * 32 + 4);
    bf16x8 af;
#pragma unroll
    for (int j = 0; j < 4; j++) { af[j] = (__bf16)h0[j]; af[4 + j] = (__bf16)h1[j]; }
#pragma unroll
    for (int dt = 0; dt < 4; dt++) {
      const short8 bs = wf[(ks * 4 + dt) * 64];
      acc[dt] = __builtin_amdgcn_mfma_f32_16x16x32_bf16(af, __builtin_bit_cast(bf16x8, bs), acc[dt], 0, 0, 0);
    }
  }
#pragma unroll
  for (int dt = 0; dt < 4; dt++) {
#pragma unroll
    for (int r = 0; r < 4; r++) {
      const int n = row0 + wave * 16 + lg * 4 + r;
      const int mstep = n >> 5, kl = n & 31;
      const int lane2 = ((kl >> 3) << 4) | lr;
      const int e = kl & 7;
      whb[((((size_t)(h * 128 + mstep) * 4 + dt) * 64 + lane2) << 3) + e] = f2us(acc[dt][r]);
    }
  }
  float as4[4], ad4[4];
#pragma unroll
  for (int dt = 0; dt < 4; dt++) {
    as4[dt] = a_src[h * kD + dt * 16 + lr];
    ad4[dt] = a_dst[h * kD + dt * 16 + lr];
  }
  float wmax = -1e30f;
#pragma unroll
  for (int r = 0; r < 4; r++) {
    float ps = acc[0][r] * as4[0] + acc[1][r] * as4[1] + acc[2][r] * as4[2] + acc[3][r] * as4[3];
    float pd = acc[0][r] * ad4[0] + acc[1][r] * ad4[1] + acc[2][r] * ad4[2] + acc[3][r] * ad4[3];
#pragma unroll
    for (int off = 1; off < 16; off <<= 1) {
      ps += __shfl_xor(ps, off);
      pd += __shfl_xor(pd, off);
    }
    const int n = row0 + wave * 16 + lg * 4 + r;
    if (lr == 0) { s_src[h * kN + n] = ps; s_dst[h * kN + n] = pd; }
    wmax = fmaxf(wmax, pd);
  }
  wmax = fmaxf(wmax, __shfl_xor(wmax, 16));
  wmax = fmaxf(wmax, __shfl_xor(wmax, 32));
  if (lane == 0) {
    const unsigned int key = (unsigned int)fmaxf(0.0f, (wmax + 512.0f) * 4096.0f) + 1u;
    atomicMax(&MhKey[h], key);
  }
}

// ---------------------------------------------------------------------------
// k_abits: adj (fp32 0/1) -> TRANSPOSED bitmask bitsT for 4 col-splits.
// Row layout (512 B): chunk = cs*8 + q*4 + lg (32 chunks x 16 B); byte `it`
// of chunk covers cols cs*1024 + it*64 + q*32 + lg*8 + [0..8).
// Each k_attn lane's 16 iteration-bytes are contiguous -> 1 dwordx4 per tile.
// ---------------------------------------------------------------------------
__global__ __launch_bounds__(256) void k_abits(const float* __restrict__ adj,
                                               unsigned char* __restrict__ bitsT) {
  const int gw = (blockIdx.x * 256 + threadIdx.x) >> 6;  // wave id, 16384 total
  const int lane = threadIdx.x & 63;
  const int r = gw >> 2, cb = gw & 3;
  const size_t ebase = (size_t)gw * 1024;
  const float* p = adj + ebase + lane;
  unsigned int myword = 0;
#pragma unroll
  for (int c = 0; c < 16; c++) {
    const unsigned long long b = __ballot(p[c * 64] != 0.0f);
    const unsigned int sel = (lane & 1) ? (unsigned int)(b >> 32) : (unsigned int)b;
    if ((lane >> 1) == c) myword = sel;
  }
  if (lane < 32) {
    const int w = cb * 32 + lane;  // word covers cols [w*32, w*32+32)
#pragma unroll
    for (int k = 0; k < 4; k++) {
      const int cb8 = w * 4 + k;       // col/8 index
      const int cs = cb8 >> 7;
      const int rem = cb8 & 127;       // = it*8 + s
      const int it = rem >> 3, s = rem & 7;
      bitsT[(size_t)r * 512 + (size_t)(cs * 8 + s) * 16 + it] =
          (unsigned char)((myword >> (8 * k)) & 0xFFu);
    }
  }
}

// p = mask * max(E1*K1, E2*K2)
__device__ __forceinline__ bf16x8 make_p2(const f32x4 E1a, const f32x4 E1b,
                                          const f32x4 E2a, const f32x4 E2b,
                                          const float K1, const float K2,
                                          const unsigned int m) {
  bf16x8 r;
#pragma unroll
  for (int j = 0; j < 4; j++) {
    const float pv = fmaxf(E1a[j] * K1, E2a[j] * K2);
    r[j] = (__bf16)((m & (1u << j)) ? pv : 0.0f);
  }
#pragma unroll
  for (int j = 0; j < 4; j++) {
    const float pv = fmaxf(E1b[j] * K1, E2b[j] * K2);
    r[4 + j] = (__bf16)((m & (16u << j)) ? pv : 0.0f);
  }
  return r;
}

// ---------------------------------------------------------------------------
// k_attn: 512 blocks = 128 rowgroups(32 rows) x 4 col-splits(1024 cols).
// 8 waves = 4 heads x 2 col-interleaves (q); 2 blocks/CU -> 4 waves/SIMD.
// Each wave: 16 units x 2 row-tiles against shared B-fragments.
// Masks in registers (2 dwordx4). q partials combined via LDS; partial
// buffers per col-split (no atomics); k_fin combines the 4 splits.
// ---------------------------------------------------------------------------
__global__ __launch_bounds__(512, 4) void k_attn(const unsigned char* __restrict__ bitsT,
                                                 const unsigned short* __restrict__ whb,
                                                 const float* __restrict__ s_src,
                                                 const float* __restrict__ s_dst,
                                                 const unsigned int* __restrict__ MhKey,
                                                 float* __restrict__ accP,
                                                 float* __restrict__ zP) {
  const int bid = blockIdx.x;
  const int rb = bid >> 2, cs = bid & 3;
  const int row0 = rb * 32;
  const int colbase = cs * 1024;
  const int t = threadIdx.x;
  const int wave = t >> 6, lane = t & 63;
  const int h = wave & 3, q = wave >> 2;
  const int lr = lane & 15, lg = lane >> 4;

  __shared__ float el1[4][1024];
  __shared__ float el2[4][1024];
  __shared__ float zx[4][32];

#pragma unroll
  for (int j = 0; j < 2; j++) {
    const int idx = t + j * 512;  // 0..1023 f32x4 slots
    const int hh = idx >> 8, c4 = (idx & 255) * 4;
    const f32x4 sd = *reinterpret_cast<const f32x4*>(s_dst + hh * kN + colbase + c4);
    f32x4 e1, e2;
#pragma unroll
    for (int i = 0; i < 4; i++) {
      const float u = sd[i] * kLog2e;
      e1[i] = __builtin_amdgcn_exp2f(u);
      e2[i] = __builtin_amdgcn_exp2f(0.2f * u);
    }
    *reinterpret_cast<f32x4*>(&el1[hh][c4]) = e1;
    *reinterpret_cast<f32x4*>(&el2[hh][c4]) = e2;
  }
  __syncthreads();

  const float M = (float)MhKey[h] * (1.0f / 4096.0f) - 512.0f;
  float K1[2], K2[2];
#pragma unroll
  for (int rt = 0; rt < 2; rt++) {
    const float A = s_src[h * kN + row0 + rt * 16 + lr];
    const float xb = A + M;
    const float B = fmaxf(xb, 0.2f * xb);
    K1[rt] = __builtin_amdgcn_exp2f((A - B) * kLog2e);
    K2[rt] = __builtin_amdgcn_exp2f((0.2f * A - B) * kLog2e);
  }

  f32x4 acc0[4] = {}, acc1[4] = {};
  f32x4 accz0 = {}, accz1 = {};
  bf16x8 ones;
#pragma unroll
  for (int e = 0; e < 8; e++) ones[e] = (__bf16)1.0f;

  // masks: 16 contiguous iteration-bytes per lane per row-tile
  const size_t mBase0 = (size_t)(row0 + lr) * 512 + (size_t)((cs << 3) + (q << 2) + lg) * 16;
  const size_t mBase1 = mBase0 + (size_t)16 * 512;
  const u32x4 m0 = *reinterpret_cast<const u32x4*>(bitsT + mBase0);  // rt0 it 0..15
  const u32x4 m1 = *reinterpret_cast<const u32x4*>(bitsT + mBase1);  // rt1 it 0..15

  const float* e1p = &el1[h][q * 32 + 8 * lg];
  const float* e2p = &el2[h][q * 32 + 8 * lg];
  const short8* wb = reinterpret_cast<const short8*>(whb) + (size_t)h * 32768 + lane;
  const int mstep0 = cs * 32 + q;

  // 2-deep B-frag prefetch (overflow prefetches land in-ws, never consumed)
  short8 bw[2][4];
#pragma unroll
  for (int s = 0; s < 2; s++) {
    const short8* p = wb + (size_t)(mstep0 + s * 2) * 256;
    bw[s][0] = p[0]; bw[s][1] = p[64]; bw[s][2] = p[128]; bw[s][3] = p[192];
  }

#define UNIT(ITC, CM0, CM1)                                                    \
  {                                                                            \
    const short8 cb0 = bw[(ITC) & 1][0], cb1 = bw[(ITC) & 1][1],               \
                 cb2 = bw[(ITC) & 1][2], cb3 = bw[(ITC) & 1][3];               \
    const short8* pp = wb + (size_t)(mstep0 + ((ITC) + 2) * 2) * 256;          \
    bw[(ITC) & 1][0] = pp[0];                                                  \
    bw[(ITC) & 1][1] = pp[64];                                                 \
    bw[(ITC) & 1][2] = pp[128];                                                \
    bw[(ITC) & 1][3] = pp[192];                                                \
    const f32x4 E1a = *reinterpret_cast<const f32x4*>(e1p + (ITC) * 64);       \
    const f32x4 E1b = *reinterpret_cast<const f32x4*>(e1p + (ITC) * 64 + 4);   \
    const f32x4 E2a = *reinterpret_cast<const f32x4*>(e2p + (ITC) * 64);       \
    const f32x4 E2b = *reinterpret_cast<const f32x4*>(e2p + (ITC) * 64 + 4);   \
    const bf16x8 P0 = make_p2(E1a, E1b, E2a, E2b, K1[0], K2[0], (CM0));        \
    const bf16x8 P1 = make_p2(E1a, E1b, E2a, E2b, K1[1], K2[1], (CM1));        \
    const bf16x8 B0 = __builtin_bit_cast(bf16x8, cb0);                         \
    const bf16x8 B1 = __builtin_bit_cast(bf16x8, cb1);                         \
    const bf16x8 B2 = __builtin_bit_cast(bf16x8, cb2);                         \
    const bf16x8 B3 = __builtin_bit_cast(bf16x8, cb3);                         \
    acc0[0] = __builtin_amdgcn_mfma_f32_16x16x32_bf16(P0, B0, acc0[0], 0, 0, 0); \
    acc1[0] = __builtin_amdgcn_mfma_f32_16x16x32_bf16(P1, B0, acc1[0], 0, 0, 0); \
    acc0[1] = __builtin_amdgcn_mfma_f32_16x16x32_bf16(P0, B1, acc0[1], 0, 0, 0); \
    acc1[1] = __builtin_amdgcn_mfma_f32_16x16x32_bf16(P1, B1, acc1[1], 0, 0, 0); \
    acc0[2] = __builtin_amdgcn_mfma_f32_16x16x32_bf16(P0, B2, acc0[2], 0, 0, 0); \
    acc1[2] = __builtin_amdgcn_mfma_f32_16x16x32_bf16(P1, B2, acc1[2], 0, 0, 0); \
    acc0[3] = __builtin_amdgcn_mfma_f32_16x16x32_bf16(P0, B3, acc0[3], 0, 0, 0); \
    acc1[3] = __builtin_amdgcn_mfma_f32_16x16x32_bf16(P1, B3, acc1[3], 0, 0, 0); \
    accz0 = __builtin_amdgcn_mfma_f32_16x16x32_bf16(P0, ones, accz0, 0, 0, 0); \
    accz1 = __builtin_amdgcn_mfma_f32_16x16x32_bf16(P1, ones, accz1, 0, 0, 0); \
  }

#pragma unroll
  for (int it = 0; it < 16; ++it) {
    const unsigned cm0 = (m0[it >> 2] >> ((it & 3) * 8)) & 0xFFu;
    const unsigned cm1 = (m1[it >> 2] >> ((it & 3) * 8)) & 0xFFu;
    UNIT(it, cm0, cm1);
  }
#undef UNIT

  // ---- q-combine via LDS (el1/el2 dead now), then single plain store ----
  __syncthreads();
  if (q == 1) {
#pragma unroll
    for (int dt = 0; dt < 4; dt++) {
      *reinterpret_cast<f32x4*>(&el1[h][(dt * 64 + lane) * 4 & 4095]) = acc0[dt];
      *reinterpret_cast<f32x4*>(&el2[h][(dt * 64 + lane) * 4 & 4095]) = acc1[dt];
    }
    if (lr == 0) {
#pragma unroll
      for (int r = 0; r < 4; r++) {
        zx[h][lg * 4 + r] = accz0[r];
        zx[h][16 + lg * 4 + r] = accz1[r];
      }
    }
  }
  __syncthreads();
  if (q == 0) {
#pragma unroll
    for (int dt = 0; dt < 4; dt++) {
      acc0[dt] += *reinterpret_cast<const f32x4*>(&el1[h][(dt * 64 + lane) * 4 & 4095]);
      acc1[dt] += *reinterpret_cast<const f32x4*>(&el2[h][(dt * 64 + lane) * 4 & 4095]);
    }
    const size_t ob = ((size_t)(cs * 4 + h) * kN + row0) * kD;
#pragma unroll
    for (int dt = 0; dt < 4; dt++)
#pragma unroll
      for (int r = 0; r < 4; r++) {
        accP[ob + (size_t)(lg * 4 + r) * kD + dt * 16 + lr] = acc0[dt][r];
        accP[ob + (size_t)(16 + lg * 4 + r) * kD + dt * 16 + lr] = acc1[dt][r];
      }
    if (lr == 0) {
      const size_t zb = (size_t)(cs * 4 + h) * kN + row0;
#pragma unroll
      for (int r = 0; r < 4; r++) {
        zP[zb + lg * 4 + r] = accz0[r] + zx[h][lg * 4 + r];
        zP[zb + 16 + lg * 4 + r] = accz1[r] + zx[h][16 + lg * 4 + r];
      }
    }
  }
}

// ---------------------------------------------------------------------------
// k_fin: out[n][h*64+d] = elu( sum_cs acc / sum_cs z )
// ---------------------------------------------------------------------------
__global__ __launch_bounds__(256) void k_fin(const float* __restrict__ accP,
                                             const float* __restrict__ zP,
                                             float* __restrict__ out) {
  const int idx = blockIdx.x * 256 + threadIdx.x;  // 262144 float4s
  const int d4 = idx & 15;
  const int hh = (idx >> 4) & 3;
  const int n = idx >> 6;
  f32x4 v = {};
  float z = 0.0f;
#pragma unroll
  for (int s = 0; s < 4; s++) {
    v += reinterpret_cast<const f32x4*>(accP)[((size_t)(s * 4 + hh) * kN + n) * 16 + d4];
    z += zP[(size_t)(s * 4 + hh) * kN + n];
  }
  const float rz = 1.0f / z;
  f32x4 o;
#pragma unroll
  for (int j = 0; j < 4; j++) {
    const float x = v[j] * rz;
    o[j] = x > 0.0f ? x : (__builtin_amdgcn_exp2f(x * kLog2e) - 1.0f);
  }
  reinterpret_cast<f32x4*>(out)[(size_t)n * 64 + hh * 16 + d4] = o;
}

extern "C" void kernel_launch(void* const* d_in, const int* in_sizes, int n_in,
                              void* d_out, int out_size, void* d_ws, size_t ws_size,
                              hipStream_t stream) {
  const float* hmat  = (const float*)d_in[0];
  const float* adj   = (const float*)d_in[1];
  const float* W     = (const float*)d_in[2];
  const float* a_src = (const float*)d_in[3];
  const float* a_dst = (const float*)d_in[4];
  float* out = (float*)d_out;

  char* ws = (char*)d_ws;
  unsigned short* whb   = (unsigned short*)(ws);             // 2 MB    @0
  unsigned short* wfrag = (unsigned short*)(ws + 0x200000);  // 128 KB (dead after k_wh)
  float* s_src  = (float*)(ws + 0x220000);                   // 64 KB
  float* s_dst  = (float*)(ws + 0x230000);                   // 64 KB
  unsigned int* MhKey = (unsigned int*)(ws + 0x240000);      // 64 B
  unsigned char* bitsT = (unsigned char*)(ws + 0x241000);    // 2 MB (transposed)
  float* accP   = (float*)(ws + 0x441000);                   // 16 MB (4 col-splits)
  float* zP     = (float*)(ws + 0x1450000);                  // 256 KB

  hipLaunchKernelGGL(k_wswz, dim3(4), dim3(256), 0, stream, W, wfrag, MhKey);
  hipLaunchKernelGGL(k_wh, dim3(256), dim3(256), 0, stream,
                     hmat, wfrag, a_src, a_dst, whb, s_src, s_dst, MhKey);
  hipLaunchKernelGGL(k_abits, dim3(4096), dim3(256), 0, stream, adj, bitsT);
  hipLaunchKernelGGL(k_attn, dim3(512), dim3(512), 0, stream,
                     bitsT, whb, s_src, s_dst, MhKey, accP, zP);
  hipLaunchKernelGGL(k_fin, dim3(1024), dim3(256), 0, stream, accP, zP, out);
}

// Round 10
// 62.953 us; speedup vs baseline: 1.0633x; 1.0366x over previous
//
#include <hip/hip_runtime.h>

typedef __attribute__((ext_vector_type(4))) float f32x4;
typedef __attribute__((ext_vector_type(8))) short short8;
typedef __attribute__((ext_vector_type(8))) __bf16 bf16x8;

constexpr int kN = 4096;
constexpr int kF = 256;
constexpr int kH = 4;
constexpr int kD = 64;
constexpr float kLog2e = 1.4426950408889634f;

__device__ __forceinline__ unsigned short f2us(float x) {
  __bf16 b = (__bf16)x;
  return __builtin_bit_cast(unsigned short, b);
}

// ---------------------------------------------------------------------------
// k_wh (fused wswz): stages W[h] -> LDS bf16 B-frags, Wh = h @ W[h] via MFMA,
// writes whb (pre-swizzled B-frag order) + s_src/s_dst + per-block pmax
// (plain store, no init/atomics needed).
// ---------------------------------------------------------------------------
__global__ __launch_bounds__(256) void k_wh(const float* __restrict__ hmat,
                                            const float* __restrict__ W,
                                            const float* __restrict__ a_src,
                                            const float* __restrict__ a_dst,
                                            unsigned short* __restrict__ whb,
                                            float* __restrict__ s_src,
                                            float* __restrict__ s_dst,
                                            float* __restrict__ pmax) {
  const int h = blockIdx.x & 3, rb = blockIdx.x >> 2;
  const int row0 = rb * 64;
  const int t = threadIdx.x;
  __shared__ unsigned short wlds[16384];
  __shared__ float bm[4];
  {
    const int d = t & 63;
    const int dt = d >> 4, dl = d & 15;
    for (int kb = 0; kb < 64; kb++) {
      const int k = kb * 4 + (t >> 6);
      const float wv = W[((size_t)h * kF + k) * kD + d];
      const int ks = k >> 5, kl = k & 31;
      const int lane2 = ((kl >> 3) << 4) | dl;
      const int e = kl & 7;
      wlds[(((ks * 4 + dt) * 64 + lane2) << 3) + e] = f2us(wv);
    }
  }
  __syncthreads();
  const int wave = t >> 6, lane = t & 63;
  const int lr = lane & 15, lg = lane >> 4;
  const int nrow = row0 + wave * 16 + lr;
  f32x4 acc[4] = {};
  const float* hrow = hmat + (size_t)nrow * kF + 8 * lg;
#pragma unroll
  for (int ks = 0; ks < 8; ks++) {
    const f32x4 h0 = *reinterpret_cast<const f32x4*>(hrow + ks * 32);
    const f32x4 h1 = *reinterpret_cast<const f32x4*>(hrow + ks * 32 + 4);
    bf16x8 af;
#pragma unroll
    for (int j = 0; j < 4; j++) { af[j] = (__bf16)h0[j]; af[4 + j] = (__bf16)h1[j]; }
#pragma unroll
    for (int dt = 0; dt < 4; dt++) {
      const short8 bs = *reinterpret_cast<const short8*>(wlds + (((ks * 4 + dt) * 64 + lane) << 3));
      acc[dt] = __builtin_amdgcn_mfma_f32_16x16x32_bf16(af, __builtin_bit_cast(bf16x8, bs), acc[dt], 0, 0, 0);
    }
  }
#pragma unroll
  for (int dt = 0; dt < 4; dt++) {
#pragma unroll
    for (int r = 0; r < 4; r++) {
      const int n = row0 + wave * 16 + lg * 4 + r;
      const int mstep = n >> 5, kl = n & 31;
      const int lane2 = ((kl >> 3) << 4) | lr;
      const int e = kl & 7;
      whb[((((size_t)(h * 128 + mstep) * 4 + dt) * 64 + lane2) << 3) + e] = f2us(acc[dt][r]);
    }
  }
  float as4[4], ad4[4];
#pragma unroll
  for (int dt = 0; dt < 4; dt++) {
    as4[dt] = a_src[h * kD + dt * 16 + lr];
    ad4[dt] = a_dst[h * kD + dt * 16 + lr];
  }
  float wmax = -1e30f;
#pragma unroll
  for (int r = 0; r < 4; r++) {
    float ps = acc[0][r] * as4[0] + acc[1][r] * as4[1] + acc[2][r] * as4[2] + acc[3][r] * as4[3];
    float pd = acc[0][r] * ad4[0] + acc[1][r] * ad4[1] + acc[2][r] * ad4[2] + acc[3][r] * ad4[3];
#pragma unroll
    for (int off = 1; off < 16; off <<= 1) {
      ps += __shfl_xor(ps, off);
      pd += __shfl_xor(pd, off);
    }
    const int n = row0 + wave * 16 + lg * 4 + r;
    if (lr == 0) { s_src[h * kN + n] = ps; s_dst[h * kN + n] = pd; }
    wmax = fmaxf(wmax, pd);
  }
  wmax = fmaxf(wmax, __shfl_xor(wmax, 16));
  wmax = fmaxf(wmax, __shfl_xor(wmax, 32));
  if (lane == 0) bm[wave] = wmax;
  __syncthreads();
  if (t == 0)
    pmax[blockIdx.x] = fmaxf(fmaxf(bm[0], bm[1]), fmaxf(bm[2], bm[3]));
}

// p = mask * max(E1*K1, E2*K2)
__device__ __forceinline__ bf16x8 make_p2(const f32x4 E1a, const f32x4 E1b,
                                          const f32x4 E2a, const f32x4 E2b,
                                          const float K1, const float K2,
                                          const unsigned int m) {
  bf16x8 r;
#pragma unroll
  for (int j = 0; j < 4; j++) {
    const float pv = fmaxf(E1a[j] * K1, E2a[j] * K2);
    r[j] = (__bf16)((m & (1u << j)) ? pv : 0.0f);
  }
#pragma unroll
  for (int j = 0; j < 4; j++) {
    const float pv = fmaxf(E1b[j] * K1, E2b[j] * K2);
    r[4 + j] = (__bf16)((m & (16u << j)) ? pv : 0.0f);
  }
  return r;
}

// ---------------------------------------------------------------------------
// k_attn (fused abits): 512 blocks = 128 rowgroups(32 rows) x 4 col-splits
// (1024 cols). 8 waves = 4 heads x 2 col-interleaves (q). Each block ballots
// its own adj tile into a 4 KB LDS bitmask (coalesced, each adj elem read
// once chip-wide), stages E-tables, preloads per-lane mask words, then runs
// the 16-unit x 2-row-tile MFMA loop. q partials via LDS; partial buffers per
// col-split (no atomics); k_fin combines.
// ---------------------------------------------------------------------------
__global__ __launch_bounds__(512, 4) void k_attn(const float* __restrict__ adj,
                                                 const unsigned short* __restrict__ whb,
                                                 const float* __restrict__ s_src,
                                                 const float* __restrict__ s_dst,
                                                 const float* __restrict__ pmax,
                                                 float* __restrict__ accP,
                                                 float* __restrict__ zP) {
  const int bid = blockIdx.x;
  const int rb = bid >> 2, cs = bid & 3;
  const int row0 = rb * 32;
  const int colbase = cs * 1024;
  const int t = threadIdx.x;
  const int wave = t >> 6, lane = t & 63;
  const int h = wave & 3, q = wave >> 2;
  const int lr = lane & 15, lg = lane >> 4;

  __shared__ float el1[4][1024];
  __shared__ float el2[4][1024];
  __shared__ unsigned long long lmask[16][32];  // [c][row_local]
  __shared__ float zx[4][32];

  // ---- adj ballots: wave handles 4 rows, 16 col-chunks of 64 ----
#pragma unroll
  for (int j = 0; j < 4; j++) {
    const int rl = wave * 4 + j;
    const float* ap = adj + (size_t)(row0 + rl) * kN + colbase + lane;
#pragma unroll
    for (int c = 0; c < 16; c++) {
      const unsigned long long b = __ballot(ap[c * 64] != 0.0f);
      if (lane == 0) lmask[c][rl] = b;
    }
  }

  // ---- E-tables ----
#pragma unroll
  for (int j = 0; j < 2; j++) {
    const int idx = t + j * 512;  // 0..1023 f32x4 slots
    const int hh = idx >> 8, c4 = (idx & 255) * 4;
    const f32x4 sd = *reinterpret_cast<const f32x4*>(s_dst + hh * kN + colbase + c4);
    f32x4 e1, e2;
#pragma unroll
    for (int i = 0; i < 4; i++) {
      const float u = sd[i] * kLog2e;
      e1[i] = __builtin_amdgcn_exp2f(u);
      e2[i] = __builtin_amdgcn_exp2f(0.2f * u);
    }
    *reinterpret_cast<f32x4*>(&el1[hh][c4]) = e1;
    *reinterpret_cast<f32x4*>(&el2[hh][c4]) = e2;
  }

  // ---- M = exact global max of s_dst[h] via pmax[64 blocks] + shfl ----
  float M = pmax[(lane << 2) | h];
#pragma unroll
  for (int off = 1; off < 64; off <<= 1) M = fmaxf(M, __shfl_xor(M, off));

  float K1[2], K2[2];
#pragma unroll
  for (int rt = 0; rt < 2; rt++) {
    const float A = s_src[h * kN + row0 + rt * 16 + lr];
    const float xb = A + M;
    const float B = fmaxf(xb, 0.2f * xb);
    K1[rt] = __builtin_amdgcn_exp2f((A - B) * kLog2e);
    K2[rt] = __builtin_amdgcn_exp2f((0.2f * A - B) * kLog2e);
  }

  __syncthreads();

  // ---- mask preload: per-lane 16 bytes per row-tile, conflict-free ----
  const unsigned char* lmaskB = reinterpret_cast<const unsigned char*>(lmask);
  const int Boff = (q << 2) | lg;
  unsigned int cw0[4], cw1[4];
#pragma unroll
  for (int w = 0; w < 4; w++) {
    unsigned int a0 = 0, a1 = 0;
#pragma unroll
    for (int d = 0; d < 4; d++) {
      const int c = w * 4 + d;
      a0 |= (unsigned int)lmaskB[c * 256 + lr * 8 + Boff] << (8 * d);
      a1 |= (unsigned int)lmaskB[c * 256 + (lr + 16) * 8 + Boff] << (8 * d);
    }
    cw0[w] = a0; cw1[w] = a1;
  }

  f32x4 acc0[4] = {}, acc1[4] = {};
  f32x4 accz0 = {}, accz1 = {};
  bf16x8 ones;
#pragma unroll
  for (int e = 0; e < 8; e++) ones[e] = (__bf16)1.0f;

  const float* e1p = &el1[h][q * 32 + 8 * lg];
  const float* e2p = &el2[h][q * 32 + 8 * lg];
  const short8* wb = reinterpret_cast<const short8*>(whb) + (size_t)h * 32768 + lane;
  const int mstep0 = cs * 32 + q;

  // 2-deep B-frag prefetch (overflow prefetches land in-ws, never consumed)
  short8 bw[2][4];
#pragma unroll
  for (int s = 0; s < 2; s++) {
    const short8* p = wb + (size_t)(mstep0 + s * 2) * 256;
    bw[s][0] = p[0]; bw[s][1] = p[64]; bw[s][2] = p[128]; bw[s][3] = p[192];
  }

#define UNIT(ITC, CM0, CM1)                                                    \
  {                                                                            \
    const short8 cb0 = bw[(ITC) & 1][0], cb1 = bw[(ITC) & 1][1],               \
                 cb2 = bw[(ITC) & 1][2], cb3 = bw[(ITC) & 1][3];               \
    const short8* pp = wb + (size_t)(mstep0 + ((ITC) + 2) * 2) * 256;          \
    bw[(ITC) & 1][0] = pp[0];                                                  \
    bw[(ITC) & 1][1] = pp[64];                                                 \
    bw[(ITC) & 1][2] = pp[128];                                                \
    bw[(ITC) & 1][3] = pp[192];                                                \
    const f32x4 E1a = *reinterpret_cast<const f32x4*>(e1p + (ITC) * 64);       \
    const f32x4 E1b = *reinterpret_cast<const f32x4*>(e1p + (ITC) * 64 + 4);   \
    const f32x4 E2a = *reinterpret_cast<const f32x4*>(e2p + (ITC) * 64);       \
    const f32x4 E2b = *reinterpret_cast<const f32x4*>(e2p + (ITC) * 64 + 4);   \
    const bf16x8 P0 = make_p2(E1a, E1b, E2a, E2b, K1[0], K2[0], (CM0));        \
    const bf16x8 P1 = make_p2(E1a, E1b, E2a, E2b, K1[1], K2[1], (CM1));        \
    const bf16x8 B0 = __builtin_bit_cast(bf16x8, cb0);                         \
    const bf16x8 B1 = __builtin_bit_cast(bf16x8, cb1);                         \
    const bf16x8 B2 = __builtin_bit_cast(bf16x8, cb2);                         \
    const bf16x8 B3 = __builtin_bit_cast(bf16x8, cb3);                         \
    acc0[0] = __builtin_amdgcn_mfma_f32_16x16x32_bf16(P0, B0, acc0[0], 0, 0, 0); \
    acc1[0] = __builtin_amdgcn_mfma_f32_16x16x32_bf16(P1, B0, acc1[0], 0, 0, 0); \
    acc0[1] = __builtin_amdgcn_mfma_f32_16x16x32_bf16(P0, B1, acc0[1], 0, 0, 0); \
    acc1[1] = __builtin_amdgcn_mfma_f32_16x16x32_bf16(P1, B1, acc1[1], 0, 0, 0); \
    acc0[2] = __builtin_amdgcn_mfma_f32_16x16x32_bf16(P0, B2, acc0[2], 0, 0, 0); \
    acc1[2] = __builtin_amdgcn_mfma_f32_16x16x32_bf16(P1, B2, acc1[2], 0, 0, 0); \
    acc0[3] = __builtin_amdgcn_mfma_f32_16x16x32_bf16(P0, B3, acc0[3], 0, 0, 0); \
    acc1[3] = __builtin_amdgcn_mfma_f32_16x16x32_bf16(P1, B3, acc1[3], 0, 0, 0); \
    accz0 = __builtin_amdgcn_mfma_f32_16x16x32_bf16(P0, ones, accz0, 0, 0, 0); \
    accz1 = __builtin_amdgcn_mfma_f32_16x16x32_bf16(P1, ones, accz1, 0, 0, 0); \
  }

#pragma unroll
  for (int it = 0; it < 16; ++it) {
    const unsigned cm0 = (cw0[it >> 2] >> ((it & 3) * 8)) & 0xFFu;
    const unsigned cm1 = (cw1[it >> 2] >> ((it & 3) * 8)) & 0xFFu;
    UNIT(it, cm0, cm1);
  }
#undef UNIT

  // ---- q-combine via LDS (el1/el2 dead now), then single plain store ----
  __syncthreads();
  if (q == 1) {
#pragma unroll
    for (int dt = 0; dt < 4; dt++) {
      *reinterpret_cast<f32x4*>(&el1[h][(dt * 64 + lane) * 4]) = acc0[dt];
      *reinterpret_cast<f32x4*>(&el2[h][(dt * 64 + lane) * 4]) = acc1[dt];
    }
    if (lr == 0) {
#pragma unroll
      for (int r = 0; r < 4; r++) {
        zx[h][lg * 4 + r] = accz0[r];
        zx[h][16 + lg * 4 + r] = accz1[r];
      }
    }
  }
  __syncthreads();
  if (q == 0) {
#pragma unroll
    for (int dt = 0; dt < 4; dt++) {
      acc0[dt] += *reinterpret_cast<const f32x4*>(&el1[h][(dt * 64 + lane) * 4]);
      acc1[dt] += *reinterpret_cast<const f32x4*>(&el2[h][(dt * 64 + lane) * 4]);
    }
    const size_t ob = ((size_t)(cs * 4 + h) * kN + row0) * kD;
#pragma unroll
    for (int dt = 0; dt < 4; dt++)
#pragma unroll
      for (int r = 0; r < 4; r++) {
        accP[ob + (size_t)(lg * 4 + r) * kD + dt * 16 + lr] = acc0[dt][r];
        accP[ob + (size_t)(16 + lg * 4 + r) * kD + dt * 16 + lr] = acc1[dt][r];
      }
    if (lr == 0) {
      const size_t zb = (size_t)(cs * 4 + h) * kN + row0;
#pragma unroll
      for (int r = 0; r < 4; r++) {
        zP[zb + lg * 4 + r] = accz0[r] + zx[h][lg * 4 + r];
        zP[zb + 16 + lg * 4 + r] = accz1[r] + zx[h][16 + lg * 4 + r];
      }
    }
  }
}

// ---------------------------------------------------------------------------
// k_fin: out[n][h*64+d] = elu( sum_cs acc / sum_cs z )
// ---------------------------------------------------------------------------
__global__ __launch_bounds__(256) void k_fin(const float* __restrict__ accP,
                                             const float* __restrict__ zP,
                                             float* __restrict__ out) {
  const int idx = blockIdx.x * 256 + threadIdx.x;  // 262144 float4s
  const int d4 = idx & 15;
  const int hh = (idx >> 4) & 3;
  const int n = idx >> 6;
  f32x4 v = {};
  float z = 0.0f;
#pragma unroll
  for (int s = 0; s < 4; s++) {
    v += reinterpret_cast<const f32x4*>(accP)[((size_t)(s * 4 + hh) * kN + n) * 16 + d4];
    z += zP[(size_t)(s * 4 + hh) * kN + n];
  }
  const float rz = 1.0f / z;
  f32x4 o;
#pragma unroll
  for (int j = 0; j < 4; j++) {
    const float x = v[j] * rz;
    o[j] = x > 0.0f ? x : (__builtin_amdgcn_exp2f(x * kLog2e) - 1.0f);
  }
  reinterpret_cast<f32x4*>(out)[(size_t)n * 64 + hh * 16 + d4] = o;
}

extern "C" void kernel_launch(void* const* d_in, const int* in_sizes, int n_in,
                              void* d_out, int out_size, void* d_ws, size_t ws_size,
                              hipStream_t stream) {
  const float* hmat  = (const float*)d_in[0];
  const float* adj   = (const float*)d_in[1];
  const float* W     = (const float*)d_in[2];
  const float* a_src = (const float*)d_in[3];
  const float* a_dst = (const float*)d_in[4];
  float* out = (float*)d_out;

  char* ws = (char*)d_ws;
  unsigned short* whb = (unsigned short*)(ws);       // 2 MB    @0
  float* s_src  = (float*)(ws + 0x200000);           // 64 KB
  float* s_dst  = (float*)(ws + 0x210000);           // 64 KB
  float* pmax   = (float*)(ws + 0x220000);           // 1 KB
  float* accP   = (float*)(ws + 0x240000);           // 16 MB (4 col-splits)
  float* zP     = (float*)(ws + 0x1240000);          // 256 KB

  hipLaunchKernelGGL(k_wh, dim3(256), dim3(256), 0, stream,
                     hmat, W, a_src, a_dst, whb, s_src, s_dst, pmax);
  hipLaunchKernelGGL(k_attn, dim3(512), dim3(512), 0, stream,
                     adj, whb, s_src, s_dst, pmax, accP, zP);
  hipLaunchKernelGGL(k_fin, dim3(1024), dim3(256), 0, stream, accP, zP, out);
}

// Round 11
// 51.316 us; speedup vs baseline: 1.3044x; 1.2268x over previous
//
#include <hip/hip_runtime.h>

typedef __attribute__((ext_vector_type(4))) float f32x4;
typedef __attribute__((ext_vector_type(8))) short short8;
typedef __attribute__((ext_vector_type(8))) __bf16 bf16x8;

constexpr int kN = 4096;
constexpr int kF = 256;
constexpr int kH = 4;
constexpr int kD = 64;
constexpr int kMP = 264;  // lmask c-stride (bytes), padded to break bank aliasing
constexpr float kLog2e = 1.4426950408889634f;

__device__ __forceinline__ unsigned short f2us(float x) {
  __bf16 b = (__bf16)x;
  return __builtin_bit_cast(unsigned short, b);
}

// ---------------------------------------------------------------------------
// k_wh (fused wswz): stages W[h] -> LDS bf16 B-frags, Wh = h @ W[h] via MFMA,
// writes whb (pre-swizzled B-frag order) + s_src/s_dst + per-block pmax.
// ---------------------------------------------------------------------------
__global__ __launch_bounds__(256) void k_wh(const float* __restrict__ hmat,
                                            const float* __restrict__ W,
                                            const float* __restrict__ a_src,
                                            const float* __restrict__ a_dst,
                                            unsigned short* __restrict__ whb,
                                            float* __restrict__ s_src,
                                            float* __restrict__ s_dst,
                                            float* __restrict__ pmax) {
  const int h = blockIdx.x & 3, rb = blockIdx.x >> 2;
  const int row0 = rb * 64;
  const int t = threadIdx.x;
  __shared__ unsigned short wlds[16384];
  __shared__ float bm[4];
  {
    const int d = t & 63;
    const int dt = d >> 4, dl = d & 15;
    for (int kb = 0; kb < 64; kb++) {
      const int k = kb * 4 + (t >> 6);
      const float wv = W[((size_t)h * kF + k) * kD + d];
      const int ks = k >> 5, kl = k & 31;
      const int lane2 = ((kl >> 3) << 4) | dl;
      const int e = kl & 7;
      wlds[(((ks * 4 + dt) * 64 + lane2) << 3) + e] = f2us(wv);
    }
  }
  __syncthreads();
  const int wave = t >> 6, lane = t & 63;
  const int lr = lane & 15, lg = lane >> 4;
  const int nrow = row0 + wave * 16 + lr;
  f32x4 acc[4] = {};
  const float* hrow = hmat + (size_t)nrow * kF + 8 * lg;
#pragma unroll
  for (int ks = 0; ks < 8; ks++) {
    const f32x4 h0 = *reinterpret_cast<const f32x4*>(hrow + ks * 32);
    const f32x4 h1 = *reinterpret_cast<const f32x4*>(hrow + ks * 32 + 4);
    bf16x8 af;
#pragma unroll
    for (int j = 0; j < 4; j++) { af[j] = (__bf16)h0[j]; af[4 + j] = (__bf16)h1[j]; }
#pragma unroll
    for (int dt = 0; dt < 4; dt++) {
      const short8 bs = *reinterpret_cast<const short8*>(wlds + (((ks * 4 + dt) * 64 + lane) << 3));
      acc[dt] = __builtin_amdgcn_mfma_f32_16x16x32_bf16(af, __builtin_bit_cast(bf16x8, bs), acc[dt], 0, 0, 0);
    }
  }
#pragma unroll
  for (int dt = 0; dt < 4; dt++) {
#pragma unroll
    for (int r = 0; r < 4; r++) {
      const int n = row0 + wave * 16 + lg * 4 + r;
      const int mstep = n >> 5, kl = n & 31;
      const int lane2 = ((kl >> 3) << 4) | lr;
      const int e = kl & 7;
      whb[((((size_t)(h * 128 + mstep) * 4 + dt) * 64 + lane2) << 3) + e] = f2us(acc[dt][r]);
    }
  }
  float as4[4], ad4[4];
#pragma unroll
  for (int dt = 0; dt < 4; dt++) {
    as4[dt] = a_src[h * kD + dt * 16 + lr];
    ad4[dt] = a_dst[h * kD + dt * 16 + lr];
  }
  float wmax = -1e30f;
#pragma unroll
  for (int r = 0; r < 4; r++) {
    float ps = acc[0][r] * as4[0] + acc[1][r] * as4[1] + acc[2][r] * as4[2] + acc[3][r] * as4[3];
    float pd = acc[0][r] * ad4[0] + acc[1][r] * ad4[1] + acc[2][r] * ad4[2] + acc[3][r] * ad4[3];
#pragma unroll
    for (int off = 1; off < 16; off <<= 1) {
      ps += __shfl_xor(ps, off);
      pd += __shfl_xor(pd, off);
    }
    const int n = row0 + wave * 16 + lg * 4 + r;
    if (lr == 0) { s_src[h * kN + n] = ps; s_dst[h * kN + n] = pd; }
    wmax = fmaxf(wmax, pd);
  }
  wmax = fmaxf(wmax, __shfl_xor(wmax, 16));
  wmax = fmaxf(wmax, __shfl_xor(wmax, 32));
  if (lane == 0) bm[wave] = wmax;
  __syncthreads();
  if (t == 0)
    pmax[blockIdx.x] = fmaxf(fmaxf(bm[0], bm[1]), fmaxf(bm[2], bm[3]));
}

// p = mask * max(E1*K1, E2*K2)
__device__ __forceinline__ bf16x8 make_p2(const f32x4 E1a, const f32x4 E1b,
                                          const f32x4 E2a, const f32x4 E2b,
                                          const float K1, const float K2,
                                          const unsigned int m) {
  bf16x8 r;
#pragma unroll
  for (int j = 0; j < 4; j++) {
    const float pv = fmaxf(E1a[j] * K1, E2a[j] * K2);
    r[j] = (__bf16)((m & (1u << j)) ? pv : 0.0f);
  }
#pragma unroll
  for (int j = 0; j < 4; j++) {
    const float pv = fmaxf(E1b[j] * K1, E2b[j] * K2);
    r[4 + j] = (__bf16)((m & (16u << j)) ? pv : 0.0f);
  }
  return r;
}

// ---------------------------------------------------------------------------
// k_attn (fused abits, pipelined): 512 blocks = 128 rowgroups(32) x 4
// col-splits(1024). 8 waves = 4 heads x 2 col-interleaves. Phase 1: each lane
// loads 16 f32x4 of adj up front (single waitcnt, one exposed latency), builds
// per-lane 8-col mask bytes with pure VALU (no ballots), stores to padded LDS.
// Phase 2: identical to the proven round-10 loop.
// ---------------------------------------------------------------------------
__global__ __launch_bounds__(512, 4) void k_attn(const float* __restrict__ adj,
                                                 const unsigned short* __restrict__ whb,
                                                 const float* __restrict__ s_src,
                                                 const float* __restrict__ s_dst,
                                                 const float* __restrict__ pmax,
                                                 float* __restrict__ accP,
                                                 float* __restrict__ zP) {
  const int bid = blockIdx.x;
  const int rb = bid >> 2, cs = bid & 3;
  const int row0 = rb * 32;
  const int colbase = cs * 1024;
  const int t = threadIdx.x;
  const int wave = t >> 6, lane = t & 63;
  const int h = wave & 3, q = wave >> 2;
  const int lr = lane & 15, lg = lane >> 4;

  __shared__ float el1[4][1024];
  __shared__ float el2[4][1024];
  __shared__ unsigned char lmaskB[16 * kMP];  // [c][row*8+s], padded stride
  __shared__ float zx[4][32];

  // ---- Phase 1: adj tile -> mask bytes (loads batched, VALU-only pack) ----
  {
    f32x4 v[16];
    const float* abase = adj + (size_t)(row0 + wave * 4) * kN + colbase;
#pragma unroll
    for (int j = 0; j < 4; j++)
#pragma unroll
      for (int p = 0; p < 4; p++) {
        const int off = ((p >> 1) << 9) + 8 * lane + ((p & 1) << 2);
        v[j * 4 + p] = *reinterpret_cast<const f32x4*>(abase + (size_t)j * kN + off);
      }
#pragma unroll
    for (int j = 0; j < 4; j++) {
      const int rl = wave * 4 + j;
#pragma unroll
      for (int half = 0; half < 2; half++) {
        unsigned int b = 0;
#pragma unroll
        for (int i = 0; i < 4; i++) {
          b |= (v[j * 4 + half * 2][i] != 0.0f ? 1u : 0u) << i;
          b |= (v[j * 4 + half * 2 + 1][i] != 0.0f ? 1u : 0u) << (4 + i);
        }
        const int o = half * 64 + lane;  // octet index 0..127
        lmaskB[(o >> 3) * kMP + rl * 8 + (o & 7)] = (unsigned char)b;
      }
    }
  }

  // ---- E-tables ----
#pragma unroll
  for (int j = 0; j < 2; j++) {
    const int idx = t + j * 512;  // 0..1023 f32x4 slots
    const int hh = idx >> 8, c4 = (idx & 255) * 4;
    const f32x4 sd = *reinterpret_cast<const f32x4*>(s_dst + hh * kN + colbase + c4);
    f32x4 e1, e2;
#pragma unroll
    for (int i = 0; i < 4; i++) {
      const float u = sd[i] * kLog2e;
      e1[i] = __builtin_amdgcn_exp2f(u);
      e2[i] = __builtin_amdgcn_exp2f(0.2f * u);
    }
    *reinterpret_cast<f32x4*>(&el1[hh][c4]) = e1;
    *reinterpret_cast<f32x4*>(&el2[hh][c4]) = e2;
  }

  // ---- M = exact global max of s_dst[h] via pmax[64 blocks] + shfl ----
  float M = pmax[(lane << 2) | h];
#pragma unroll
  for (int off = 1; off < 64; off <<= 1) M = fmaxf(M, __shfl_xor(M, off));

  float K1[2], K2[2];
#pragma unroll
  for (int rt = 0; rt < 2; rt++) {
    const float A = s_src[h * kN + row0 + rt * 16 + lr];
    const float xb = A + M;
    const float B = fmaxf(xb, 0.2f * xb);
    K1[rt] = __builtin_amdgcn_exp2f((A - B) * kLog2e);
    K2[rt] = __builtin_amdgcn_exp2f((0.2f * A - B) * kLog2e);
  }

  __syncthreads();

  // ---- mask preload: per-lane 16 bytes per row-tile ----
  const int Boff = (q << 2) | lg;
  unsigned int cw0[4], cw1[4];
#pragma unroll
  for (int w = 0; w < 4; w++) {
    unsigned int a0 = 0, a1 = 0;
#pragma unroll
    for (int d = 0; d < 4; d++) {
      const int c = w * 4 + d;
      a0 |= (unsigned int)lmaskB[c * kMP + lr * 8 + Boff] << (8 * d);
      a1 |= (unsigned int)lmaskB[c * kMP + (lr + 16) * 8 + Boff] << (8 * d);
    }
    cw0[w] = a0; cw1[w] = a1;
  }

  f32x4 acc0[4] = {}, acc1[4] = {};
  f32x4 accz0 = {}, accz1 = {};
  bf16x8 ones;
#pragma unroll
  for (int e = 0; e < 8; e++) ones[e] = (__bf16)1.0f;

  const float* e1p = &el1[h][q * 32 + 8 * lg];
  const float* e2p = &el2[h][q * 32 + 8 * lg];
  const short8* wb = reinterpret_cast<const short8*>(whb) + (size_t)h * 32768 + lane;
  const int mstep0 = cs * 32 + q;

  // 2-deep B-frag prefetch (overflow prefetches land in-ws, never consumed)
  short8 bw[2][4];
#pragma unroll
  for (int s = 0; s < 2; s++) {
    const short8* p = wb + (size_t)(mstep0 + s * 2) * 256;
    bw[s][0] = p[0]; bw[s][1] = p[64]; bw[s][2] = p[128]; bw[s][3] = p[192];
  }

#define UNIT(ITC, CM0, CM1)                                                    \
  {                                                                            \
    const short8 cb0 = bw[(ITC) & 1][0], cb1 = bw[(ITC) & 1][1],               \
                 cb2 = bw[(ITC) & 1][2], cb3 = bw[(ITC) & 1][3];               \
    const short8* pp = wb + (size_t)(mstep0 + ((ITC) + 2) * 2) * 256;          \
    bw[(ITC) & 1][0] = pp[0];                                                  \
    bw[(ITC) & 1][1] = pp[64];                                                 \
    bw[(ITC) & 1][2] = pp[128];                                                \
    bw[(ITC) & 1][3] = pp[192];                                                \
    const f32x4 E1a = *reinterpret_cast<const f32x4*>(e1p + (ITC) * 64);       \
    const f32x4 E1b = *reinterpret_cast<const f32x4*>(e1p + (ITC) * 64 + 4);   \
    const f32x4 E2a = *reinterpret_cast<const f32x4*>(e2p + (ITC) * 64);       \
    const f32x4 E2b = *reinterpret_cast<const f32x4*>(e2p + (ITC) * 64 + 4);   \
    const bf16x8 P0 = make_p2(E1a, E1b, E2a, E2b, K1[0], K2[0], (CM0));        \
    const bf16x8 P1 = make_p2(E1a, E1b, E2a, E2b, K1[1], K2[1], (CM1));        \
    const bf16x8 B0 = __builtin_bit_cast(bf16x8, cb0);                         \
    const bf16x8 B1 = __builtin_bit_cast(bf16x8, cb1);                         \
    const bf16x8 B2 = __builtin_bit_cast(bf16x8, cb2);                         \
    const bf16x8 B3 = __builtin_bit_cast(bf16x8, cb3);                         \
    acc0[0] = __builtin_amdgcn_mfma_f32_16x16x32_bf16(P0, B0, acc0[0], 0, 0, 0); \
    acc1[0] = __builtin_amdgcn_mfma_f32_16x16x32_bf16(P1, B0, acc1[0], 0, 0, 0); \
    acc0[1] = __builtin_amdgcn_mfma_f32_16x16x32_bf16(P0, B1, acc0[1], 0, 0, 0); \
    acc1[1] = __builtin_amdgcn_mfma_f32_16x16x32_bf16(P1, B1, acc1[1], 0, 0, 0); \
    acc0[2] = __builtin_amdgcn_mfma_f32_16x16x32_bf16(P0, B2, acc0[2], 0, 0, 0); \
    acc1[2] = __builtin_amdgcn_mfma_f32_16x16x32_bf16(P1, B2, acc1[2], 0, 0, 0); \
    acc0[3] = __builtin_amdgcn_mfma_f32_16x16x32_bf16(P0, B3, acc0[3], 0, 0, 0); \
    acc1[3] = __builtin_amdgcn_mfma_f32_16x16x32_bf16(P1, B3, acc1[3], 0, 0, 0); \
    accz0 = __builtin_amdgcn_mfma_f32_16x16x32_bf16(P0, ones, accz0, 0, 0, 0); \
    accz1 = __builtin_amdgcn_mfma_f32_16x16x32_bf16(P1, ones, accz1, 0, 0, 0); \
  }

#pragma unroll
  for (int it = 0; it < 16; ++it) {
    const unsigned cm0 = (cw0[it >> 2] >> ((it & 3) * 8)) & 0xFFu;
    const unsigned cm1 = (cw1[it >> 2] >> ((it & 3) * 8)) & 0xFFu;
    UNIT(it, cm0, cm1);
  }
#undef UNIT

  // ---- q-combine via LDS (el1/el2 dead now), then single plain store ----
  __syncthreads();
  if (q == 1) {
#pragma unroll
    for (int dt = 0; dt < 4; dt++) {
      *reinterpret_cast<f32x4*>(&el1[h][(dt * 64 + lane) * 4]) = acc0[dt];
      *reinterpret_cast<f32x4*>(&el2[h][(dt * 64 + lane) * 4]) = acc1[dt];
    }
    if (lr == 0) {
#pragma unroll
      for (int r = 0; r < 4; r++) {
        zx[h][lg * 4 + r] = accz0[r];
        zx[h][16 + lg * 4 + r] = accz1[r];
      }
    }
  }
  __syncthreads();
  if (q == 0) {
#pragma unroll
    for (int dt = 0; dt < 4; dt++) {
      acc0[dt] += *reinterpret_cast<const f32x4*>(&el1[h][(dt * 64 + lane) * 4]);
      acc1[dt] += *reinterpret_cast<const f32x4*>(&el2[h][(dt * 64 + lane) * 4]);
    }
    const size_t ob = ((size_t)(cs * 4 + h) * kN + row0) * kD;
#pragma unroll
    for (int dt = 0; dt < 4; dt++)
#pragma unroll
      for (int r = 0; r < 4; r++) {
        accP[ob + (size_t)(lg * 4 + r) * kD + dt * 16 + lr] = acc0[dt][r];
        accP[ob + (size_t)(16 + lg * 4 + r) * kD + dt * 16 + lr] = acc1[dt][r];
      }
    if (lr == 0) {
      const size_t zb = (size_t)(cs * 4 + h) * kN + row0;
#pragma unroll
      for (int r = 0; r < 4; r++) {
        zP[zb + lg * 4 + r] = accz0[r] + zx[h][lg * 4 + r];
        zP[zb + 16 + lg * 4 + r] = accz1[r] + zx[h][16 + lg * 4 + r];
      }
    }
  }
}

// ---------------------------------------------------------------------------
// k_fin: out[n][h*64+d] = elu( sum_cs acc / sum_cs z )
// ---------------------------------------------------------------------------
__global__ __launch_bounds__(256) void k_fin(const float* __restrict__ accP,
                                             const float* __restrict__ zP,
                                             float* __restrict__ out) {
  const int idx = blockIdx.x * 256 + threadIdx.x;  // 262144 float4s
  const int d4 = idx & 15;
  const int hh = (idx >> 4) & 3;
  const int n = idx >> 6;
  f32x4 v = {};
  float z = 0.0f;
#pragma unroll
  for (int s = 0; s < 4; s++) {
    v += reinterpret_cast<const f32x4*>(accP)[((size_t)(s * 4 + hh) * kN + n) * 16 + d4];
    z += zP[(size_t)(s * 4 + hh) * kN + n];
  }
  const float rz = 1.0f / z;
  f32x4 o;
#pragma unroll
  for (int j = 0; j < 4; j++) {
    const float x = v[j] * rz;
    o[j] = x > 0.0f ? x : (__builtin_amdgcn_exp2f(x * kLog2e) - 1.0f);
  }
  reinterpret_cast<f32x4*>(out)[(size_t)n * 64 + hh * 16 + d4] = o;
}

extern "C" void kernel_launch(void* const* d_in, const int* in_sizes, int n_in,
                              void* d_out, int out_size, void* d_ws, size_t ws_size,
                              hipStream_t stream) {
  const float* hmat  = (const float*)d_in[0];
  const float* adj   = (const float*)d_in[1];
  const float* W     = (const float*)d_in[2];
  const float* a_src = (const float*)d_in[3];
  const float* a_dst = (const float*)d_in[4];
  float* out = (float*)d_out;

  char* ws = (char*)d_ws;
  unsigned short* whb = (unsigned short*)(ws);       // 2 MB    @0
  float* s_src  = (float*)(ws + 0x200000);           // 64 KB
  float* s_dst  = (float*)(ws + 0x210000);           // 64 KB
  float* pmax   = (float*)(ws + 0x220000);           // 1 KB
  float* accP   = (float*)(ws + 0x240000);           // 16 MB (4 col-splits)
  float* zP     = (float*)(ws + 0x1240000);          // 256 KB

  hipLaunchKernelGGL(k_wh, dim3(256), dim3(256), 0, stream,
                     hmat, W, a_src, a_dst, whb, s_src, s_dst, pmax);
  hipLaunchKernelGGL(k_attn, dim3(512), dim3(512), 0, stream,
                     adj, whb, s_src, s_dst, pmax, accP, zP);
  hipLaunchKernelGGL(k_fin, dim3(1024), dim3(256), 0, stream, accP, zP, out);
}